// Round 15
// baseline (8081.634 us; speedup 1.0000x reference)
//
#include <hip/hip_runtime.h>

#define NN 512
#define DD 32
#define TT 8192

typedef float v4f __attribute__((ext_vector_type(4)));
typedef float v2f __attribute__((ext_vector_type(2)));
typedef float v16f __attribute__((ext_vector_type(16)));
typedef __attribute__((address_space(3))) float lds_f;

constexpr float F_OMEGA = 10.0f;
constexpr float F_DT = 1e-3f;
constexpr float F_TWO_PI = 6.28318530717958647692f;
constexpr float F_INV_TWO_PI = 0.15915494309189533577f;

__device__ __forceinline__ void barrier_lgkm() {
    asm volatile("s_waitcnt lgkmcnt(0)\n\ts_barrier" ::: "memory");
}

#define DSR128(dst, addr, off) \
    asm volatile("ds_read_b128 %0, %1 offset:" #off : "=v"(dst) : "v"(addr))

#define SL16(dst, ptr, off) \
    asm volatile("s_load_dwordx16 %0, %1, " #off : "=s"(dst) : "s"(ptr))
#define SL1(dst, ptr) \
    asm volatile("s_load_dword %0, %1, 0x0" : "=s"(dst) : "s"(ptr))

#define DPP_ADD(x, ctrl, rmask)                                                 \
    {                                                                           \
        int _t = __builtin_amdgcn_update_dpp(0, __float_as_int(x),              \
                                             (ctrl), (rmask), 0xf, true);       \
        (x) += __int_as_float(_t);                                              \
    }

__device__ __forceinline__ float wave_reduce_to_lane63(float x) {
    DPP_ADD(x, 0xB1, 0xf);   // + xor1
    DPP_ADD(x, 0x4E, 0xf);   // + xor2
    DPP_ADD(x, 0x141, 0xf);  // + xor4
    DPP_ADD(x, 0x140, 0xf);  // + xor8
    DPP_ADD(x, 0x142, 0xa);  // row_bcast15
    DPP_ADD(x, 0x143, 0xc);  // row_bcast31
    return x;                // lane 63 = full wave sum
}

// Expand two v16f (SGPR-resident) into 16 v2f pair views (SGPR subregs).
#define MKP(dst, lo, hi)                                                        \
    dst[0]  = __builtin_shufflevector(lo, lo, 0, 1);                            \
    dst[1]  = __builtin_shufflevector(lo, lo, 2, 3);                            \
    dst[2]  = __builtin_shufflevector(lo, lo, 4, 5);                            \
    dst[3]  = __builtin_shufflevector(lo, lo, 6, 7);                            \
    dst[4]  = __builtin_shufflevector(lo, lo, 8, 9);                            \
    dst[5]  = __builtin_shufflevector(lo, lo, 10, 11);                          \
    dst[6]  = __builtin_shufflevector(lo, lo, 12, 13);                          \
    dst[7]  = __builtin_shufflevector(lo, lo, 14, 15);                          \
    dst[8]  = __builtin_shufflevector(hi, hi, 0, 1);                            \
    dst[9]  = __builtin_shufflevector(hi, hi, 2, 3);                            \
    dst[10] = __builtin_shufflevector(hi, hi, 4, 5);                            \
    dst[11] = __builtin_shufflevector(hi, hi, 6, 7);                            \
    dst[12] = __builtin_shufflevector(hi, hi, 8, 9);                            \
    dst[13] = __builtin_shufflevector(hi, hi, 10, 11);                          \
    dst[14] = __builtin_shufflevector(hi, hi, 12, 13);                          \
    dst[15] = __builtin_shufflevector(hi, hi, 14, 15);

// x pair operand lists for the asm blobs (16 "s" inputs each).
#define XIN(x) \
    "s"(x[0]), "s"(x[1]), "s"(x[2]), "s"(x[3]), "s"(x[4]), "s"(x[5]), \
    "s"(x[6]), "s"(x[7]), "s"(x[8]), "s"(x[9]), "s"(x[10]), "s"(x[11]), \
    "s"(x[12]), "s"(x[13]), "s"(x[14]), "s"(x[15])

__global__ __launch_bounds__(512, 2) void deerskin(
    const float* __restrict__ Xr, const float* __restrict__ Xi,
    const float* __restrict__ Tg,
    const float* __restrict__ W0r, const float* __restrict__ W0i,
    const float* __restrict__ Phi0, const float* __restrict__ Beta0,
    float* __restrict__ outs, float* __restrict__ betas, float* __restrict__ gammas)
{
    // Only remaining LDS: 16-float double-buffered partial array.
    __shared__ __align__(16) float sP[16];

    const int n = threadIdx.x;
    const int lane = n & 63;
    const int wid = n >> 6;

    // ---- W state PINNED to physical ArchVGPRs v[64:127] (R6) ----
    v16f wrA, wrB, wiA, wiB;
    {
        const v16f* r = (const v16f*)(W0r + n * DD);
        const v16f* i = (const v16f*)(W0i + n * DD);
        v16f t0 = r[0], t1 = r[1], t2 = i[0], t3 = i[1];
        asm volatile("" : "={v[64:79]}"(wrA) : "0"(t0));
        asm volatile("" : "={v[80:95]}"(wrB) : "0"(t1));
        asm volatile("" : "={v[96:111]}"(wiA) : "0"(t2));
        asm volatile("" : "={v[112:127]}"(wiB) : "0"(t3));
    }

    // ---- tw staging PINNED to v[128:191] ----
    // R12 confirmed the fill model (busy exactly constant, idle -150cy).
    // R14 = R12 + the xi-half of tw WOVEN into the feedback dep-chain after
    // the sP tie (volatile asm fences pin the interleave). R13 lesson: the
    // x(t+1) prefetch must stay AFTER the last xi_ use (after WU) — two x
    // generations cannot coexist in SGPRs (async s_load dst over live data).
    v16f twA, twB, twC, twD;
    {
        v16f z = {0,0,0,0,0,0,0,0,0,0,0,0,0,0,0,0};
        asm volatile("" : "={v[128:143]}"(twA) : "0"(z));
        asm volatile("" : "={v[144:159]}"(twB) : "0"(z));
        asm volatile("" : "={v[160:175]}"(twC) : "0"(z));
        asm volatile("" : "={v[176:191]}"(twD) : "0"(z));
    }

    float phi = Phi0[n];
    float beta = Beta0[n];
    float lt = 0.0f;
    float err = 0.0f;

    // Loop-carried SGPR-resident x(t).
    v16f sxr0, sxr1, sxi0, sxi1;
    float stgt;

    // ---- prologue: issue x(0) scalar loads (drained by the t=0 tie-wait).
    SL16(sxr0, Xr, 0x0); SL16(sxr1, Xr, 0x40);
    SL16(sxi0, Xi, 0x0); SL16(sxi1, Xi, 0x40);
    SL1(stgt, Tg);

    for (int t = 0; t < TT; ++t) {
        // ---- 1. x-independent precompute (beta-dependent arm) ----
        const float gamma = __expf(-0.5f * beta);
        const float dtl = gamma * F_DT;
        lt += dtl;
        const float theta = fmaf(F_OMEGA, lt, phi);
        float rev = theta * F_INV_TWO_PI;
        rev -= floorf(rev);
        const float s = __builtin_amdgcn_sinf(rev);
        const float c = __builtin_amdgcn_cosf(rev);
        const float a_sA = 1.0f - __expf(-2.0f * F_DT * (gamma + 1e-6f));
        const float a_sB = 1.0f - __expf(-F_DT / 0.03f);

        // ---- 2. tie-wait for x(t) ----
        asm volatile("s_waitcnt lgkmcnt(0)"
            : "+s"(sxr0), "+s"(sxr1), "+s"(sxi0), "+s"(sxi1), "+s"(stgt)
            :: "memory");
        const float tgt = stgt;

        v2f xr_[16], xi_[16];
        MKP(xr_, sxr0, sxr1);
        MKP(xi_, sxi0, sxi1);

        // ---- 3. Z = W @ x: two blobs, pinned-W pairs referenced directly.
        // Chain order per accumulator identical to R5/R6 -> bit-identical FP.
        v2f arr0, arr1, aii0, aii1, ari0, ari1, air0, air1;
        asm volatile(
            "v_pk_mul_f32 %0, v[64:65], %8\n\t"
            "v_pk_mul_f32 %1, v[66:67], %9\n\t"
            "v_pk_mul_f32 %2, v[96:97], %8\n\t"
            "v_pk_mul_f32 %3, v[98:99], %9\n\t"
            "v_pk_fma_f32 %0, v[68:69], %10, %0\n\t"
            "v_pk_fma_f32 %1, v[70:71], %11, %1\n\t"
            "v_pk_fma_f32 %2, v[100:101], %10, %2\n\t"
            "v_pk_fma_f32 %3, v[102:103], %11, %3\n\t"
            "v_pk_fma_f32 %0, v[72:73], %12, %0\n\t"
            "v_pk_fma_f32 %1, v[74:75], %13, %1\n\t"
            "v_pk_fma_f32 %2, v[104:105], %12, %2\n\t"
            "v_pk_fma_f32 %3, v[106:107], %13, %3\n\t"
            "v_pk_fma_f32 %0, v[76:77], %14, %0\n\t"
            "v_pk_fma_f32 %1, v[78:79], %15, %1\n\t"
            "v_pk_fma_f32 %2, v[108:109], %14, %2\n\t"
            "v_pk_fma_f32 %3, v[110:111], %15, %3\n\t"
            "v_pk_fma_f32 %0, v[80:81], %16, %0\n\t"
            "v_pk_fma_f32 %1, v[82:83], %17, %1\n\t"
            "v_pk_fma_f32 %2, v[112:113], %16, %2\n\t"
            "v_pk_fma_f32 %3, v[114:115], %17, %3\n\t"
            "v_pk_fma_f32 %0, v[84:85], %18, %0\n\t"
            "v_pk_fma_f32 %1, v[86:87], %19, %1\n\t"
            "v_pk_fma_f32 %2, v[116:117], %18, %2\n\t"
            "v_pk_fma_f32 %3, v[118:119], %19, %3\n\t"
            "v_pk_fma_f32 %0, v[88:89], %20, %0\n\t"
            "v_pk_fma_f32 %1, v[90:91], %21, %1\n\t"
            "v_pk_fma_f32 %2, v[120:121], %20, %2\n\t"
            "v_pk_fma_f32 %3, v[122:123], %21, %3\n\t"
            "v_pk_fma_f32 %0, v[92:93], %22, %0\n\t"
            "v_pk_fma_f32 %1, v[94:95], %23, %1\n\t"
            "v_pk_fma_f32 %2, v[124:125], %22, %2\n\t"
            "v_pk_fma_f32 %3, v[126:127], %23, %3"
            : "=&v"(arr0), "=&v"(arr1), "=&v"(air0), "=&v"(air1)
            : "{v[64:79]}"(wrA), "{v[80:95]}"(wrB),
              "{v[96:111]}"(wiA), "{v[112:127]}"(wiB), XIN(xr_));
        asm volatile(
            "v_pk_mul_f32 %0, v[96:97], %8\n\t"
            "v_pk_mul_f32 %1, v[98:99], %9\n\t"
            "v_pk_mul_f32 %2, v[64:65], %8\n\t"
            "v_pk_mul_f32 %3, v[66:67], %9\n\t"
            "v_pk_fma_f32 %0, v[100:101], %10, %0\n\t"
            "v_pk_fma_f32 %1, v[102:103], %11, %1\n\t"
            "v_pk_fma_f32 %2, v[68:69], %10, %2\n\t"
            "v_pk_fma_f32 %3, v[70:71], %11, %3\n\t"
            "v_pk_fma_f32 %0, v[104:105], %12, %0\n\t"
            "v_pk_fma_f32 %1, v[106:107], %13, %1\n\t"
            "v_pk_fma_f32 %2, v[72:73], %12, %2\n\t"
            "v_pk_fma_f32 %3, v[74:75], %13, %3\n\t"
            "v_pk_fma_f32 %0, v[108:109], %14, %0\n\t"
            "v_pk_fma_f32 %1, v[110:111], %15, %1\n\t"
            "v_pk_fma_f32 %2, v[76:77], %14, %2\n\t"
            "v_pk_fma_f32 %3, v[78:79], %15, %3\n\t"
            "v_pk_fma_f32 %0, v[112:113], %16, %0\n\t"
            "v_pk_fma_f32 %1, v[114:115], %17, %1\n\t"
            "v_pk_fma_f32 %2, v[80:81], %16, %2\n\t"
            "v_pk_fma_f32 %3, v[82:83], %17, %3\n\t"
            "v_pk_fma_f32 %0, v[116:117], %18, %0\n\t"
            "v_pk_fma_f32 %1, v[118:119], %19, %1\n\t"
            "v_pk_fma_f32 %2, v[84:85], %18, %2\n\t"
            "v_pk_fma_f32 %3, v[86:87], %19, %3\n\t"
            "v_pk_fma_f32 %0, v[120:121], %20, %0\n\t"
            "v_pk_fma_f32 %1, v[122:123], %21, %1\n\t"
            "v_pk_fma_f32 %2, v[88:89], %20, %2\n\t"
            "v_pk_fma_f32 %3, v[90:91], %21, %3\n\t"
            "v_pk_fma_f32 %0, v[124:125], %22, %0\n\t"
            "v_pk_fma_f32 %1, v[126:127], %23, %1\n\t"
            "v_pk_fma_f32 %2, v[92:93], %22, %2\n\t"
            "v_pk_fma_f32 %3, v[94:95], %23, %3"
            : "=&v"(aii0), "=&v"(aii1), "=&v"(ari0), "=&v"(ari1)
            : "{v[64:79]}"(wrA), "{v[80:95]}"(wrB),
              "{v[96:111]}"(wiA), "{v[112:127]}"(wiB), XIN(xi_));

        const float hArr = (arr0.x + arr0.y) + (arr1.x + arr1.y);
        const float hAii = (aii0.x + aii0.y) + (aii1.x + aii1.y);
        const float hAri = (ari0.x + ari0.y) + (ari1.x + ari1.y);
        const float hAir = (air0.x + air0.y) + (air1.x + air1.y);
        const float zr = hArr - hAii;
        const float zi = hAri + hAir;

        // Y = |Z| * relu(cos(theta - angle(Z))) == relu(zr*cos + zi*sin)
        const float Y = fmaxf(fmaf(zr, c, zi * s), 0.0f);

        // ---- 4. reduce 512 -> 1: DPP wave sum, 8 partials via LDS ----
        float v = wave_reduce_to_lane63(Y * c);
        if (lane == 63) sP[((t & 1) << 3) + wid] = v;

        // ---- 5. pre-barrier tail ----
        const float inv_t = 1.0f / (fabsf(tgt) + 0.01f);
        const float yy = Y * Y;
        const float g = 0.05f * Y * dtl;
        const v2f g2 = {g, g};
        phi += (2.0f / (float)NN) * (-tgt * s) * dtl;
        phi = phi - F_TWO_PI * floorf(phi * F_INV_TWO_PI);
        gammas[t * NN + n] = gamma;   // gamma from OLD beta, per reference

        // ---- 6. barrier (drains only lane63's sP ds_write) ----
        barrier_lgkm();

        // ---- 7. sP reads ISSUED, then the xr-half of tw fills the ds_read
        // latency (16 pk x 2 waves = 128cy issue vs ~120cy latency).
        const unsigned lsp =
            (unsigned)(unsigned long long)(lds_f*)&sP[(t & 1) << 3];
        v4f p0, p1;
        DSR128(p0, lsp, 0); DSR128(p1, lsp, 16);
        asm volatile(
            "v_pk_mul_f32 v[128:129], %[g2], %[x0]\n\t"
            "v_pk_mul_f32 v[130:131], %[g2], %[x1]\n\t"
            "v_pk_mul_f32 v[132:133], %[g2], %[x2]\n\t"
            "v_pk_mul_f32 v[134:135], %[g2], %[x3]\n\t"
            "v_pk_mul_f32 v[136:137], %[g2], %[x4]\n\t"
            "v_pk_mul_f32 v[138:139], %[g2], %[x5]\n\t"
            "v_pk_mul_f32 v[140:141], %[g2], %[x6]\n\t"
            "v_pk_mul_f32 v[142:143], %[g2], %[x7]\n\t"
            "v_pk_mul_f32 v[144:145], %[g2], %[x8]\n\t"
            "v_pk_mul_f32 v[146:147], %[g2], %[x9]\n\t"
            "v_pk_mul_f32 v[148:149], %[g2], %[x10]\n\t"
            "v_pk_mul_f32 v[150:151], %[g2], %[x11]\n\t"
            "v_pk_mul_f32 v[152:153], %[g2], %[x12]\n\t"
            "v_pk_mul_f32 v[154:155], %[g2], %[x13]\n\t"
            "v_pk_mul_f32 v[156:157], %[g2], %[x14]\n\t"
            "v_pk_mul_f32 v[158:159], %[g2], %[x15]"
            : "+{v[128:143]}"(twA), "+{v[144:159]}"(twB)
            : [g2]"v"(g2),
              [x0]"s"(xr_[0]), [x1]"s"(xr_[1]), [x2]"s"(xr_[2]), [x3]"s"(xr_[3]),
              [x4]"s"(xr_[4]), [x5]"s"(xr_[5]), [x6]"s"(xr_[6]), [x7]"s"(xr_[7]),
              [x8]"s"(xr_[8]), [x9]"s"(xr_[9]), [x10]"s"(xr_[10]), [x11]"s"(xr_[11]),
              [x12]"s"(xr_[12]), [x13]"s"(xr_[13]), [x14]"s"(xr_[14]), [x15]"s"(xr_[15]));

        asm volatile("s_waitcnt lgkmcnt(0)" : "+v"(p0), "+v"(p1) :: "memory");

        // ---- 8. feedback chain WOVEN with the xi-half of tw (R14 change).
        // Volatile asm fences pin the interleave; the wave issues tw during
        // its own feedback dep gaps. FP ops identical to R12.
        const float l1a = p0.x + p0.y;
        const float l1b = p0.z + p0.w;
        const float l1c = p1.x + p1.y;
        const float l1d = p1.z + p1.w;

        // tw xi chunk 1 (8 pk) — fills the out-tree dep gaps.
        asm volatile(
            "v_pk_mul_f32 v[160:161], %[g2], %[x0]\n\t"
            "v_pk_mul_f32 v[162:163], %[g2], %[x1]\n\t"
            "v_pk_mul_f32 v[164:165], %[g2], %[x2]\n\t"
            "v_pk_mul_f32 v[166:167], %[g2], %[x3]\n\t"
            "v_pk_mul_f32 v[168:169], %[g2], %[x4]\n\t"
            "v_pk_mul_f32 v[170:171], %[g2], %[x5]\n\t"
            "v_pk_mul_f32 v[172:173], %[g2], %[x6]\n\t"
            "v_pk_mul_f32 v[174:175], %[g2], %[x7]"
            : "+{v[160:175]}"(twC)
            : [g2]"v"(g2),
              [x0]"s"(xi_[0]), [x1]"s"(xi_[1]), [x2]"s"(xi_[2]), [x3]"s"(xi_[3]),
              [x4]"s"(xi_[4]), [x5]"s"(xi_[5]), [x6]"s"(xi_[6]), [x7]"s"(xi_[7]));

        const float l2a = l1a + l1b;
        const float l2b = l1c + l1d;
        const float out = l2a + l2b;
        const float raw = fabsf(tgt - out);

        // tw xi chunk 2 (8 pk) — fills the err/exp dep gaps.
        asm volatile(
            "v_pk_mul_f32 v[176:177], %[g2], %[x0]\n\t"
            "v_pk_mul_f32 v[178:179], %[g2], %[x1]\n\t"
            "v_pk_mul_f32 v[180:181], %[g2], %[x2]\n\t"
            "v_pk_mul_f32 v[182:183], %[g2], %[x3]\n\t"
            "v_pk_mul_f32 v[184:185], %[g2], %[x4]\n\t"
            "v_pk_mul_f32 v[186:187], %[g2], %[x5]\n\t"
            "v_pk_mul_f32 v[188:189], %[g2], %[x6]\n\t"
            "v_pk_mul_f32 v[190:191], %[g2], %[x7]"
            : "+{v[176:191]}"(twD)
            : [g2]"v"(g2),
              [x0]"s"(xi_[8]), [x1]"s"(xi_[9]), [x2]"s"(xi_[10]), [x3]"s"(xi_[11]),
              [x4]"s"(xi_[12]), [x5]"s"(xi_[13]), [x6]"s"(xi_[14]), [x7]"s"(xi_[15]));

        err = 0.99f * err + 0.01f * raw;
        const float rel = err * inv_t;
        const float btg = 3.5f * __expf(-5.0f * rel);
        const float a_s = (btg > beta) ? a_sA : a_sB;
        float bnew = beta + a_s * (btg - beta);
        bnew = fminf(fmaxf(bnew, 0.005f), 5.0f);

        // ---- 9. W = W*m1 + tw: only 32 feedback-dependent fmas remain ----
        const float k = (bnew * yy) * dtl;
        const float m1 = 1.0f - k;
        const v2f m12 = {m1, m1};
        asm volatile(
            "v_pk_fma_f32 v[64:65], v[64:65], %[m1], v[128:129]\n\t"
            "v_pk_fma_f32 v[66:67], v[66:67], %[m1], v[130:131]\n\t"
            "v_pk_fma_f32 v[68:69], v[68:69], %[m1], v[132:133]\n\t"
            "v_pk_fma_f32 v[70:71], v[70:71], %[m1], v[134:135]\n\t"
            "v_pk_fma_f32 v[72:73], v[72:73], %[m1], v[136:137]\n\t"
            "v_pk_fma_f32 v[74:75], v[74:75], %[m1], v[138:139]\n\t"
            "v_pk_fma_f32 v[76:77], v[76:77], %[m1], v[140:141]\n\t"
            "v_pk_fma_f32 v[78:79], v[78:79], %[m1], v[142:143]\n\t"
            "v_pk_fma_f32 v[80:81], v[80:81], %[m1], v[144:145]\n\t"
            "v_pk_fma_f32 v[82:83], v[82:83], %[m1], v[146:147]\n\t"
            "v_pk_fma_f32 v[84:85], v[84:85], %[m1], v[148:149]\n\t"
            "v_pk_fma_f32 v[86:87], v[86:87], %[m1], v[150:151]\n\t"
            "v_pk_fma_f32 v[88:89], v[88:89], %[m1], v[152:153]\n\t"
            "v_pk_fma_f32 v[90:91], v[90:91], %[m1], v[154:155]\n\t"
            "v_pk_fma_f32 v[92:93], v[92:93], %[m1], v[156:157]\n\t"
            "v_pk_fma_f32 v[94:95], v[94:95], %[m1], v[158:159]"
            : "+{v[64:79]}"(wrA), "+{v[80:95]}"(wrB)
            : [m1]"v"(m12), "{v[128:143]}"(twA), "{v[144:159]}"(twB));
        asm volatile(
            "v_pk_fma_f32 v[96:97], v[96:97], %[m1], v[160:161]\n\t"
            "v_pk_fma_f32 v[98:99], v[98:99], %[m1], v[162:163]\n\t"
            "v_pk_fma_f32 v[100:101], v[100:101], %[m1], v[164:165]\n\t"
            "v_pk_fma_f32 v[102:103], v[102:103], %[m1], v[166:167]\n\t"
            "v_pk_fma_f32 v[104:105], v[104:105], %[m1], v[168:169]\n\t"
            "v_pk_fma_f32 v[106:107], v[106:107], %[m1], v[170:171]\n\t"
            "v_pk_fma_f32 v[108:109], v[108:109], %[m1], v[172:173]\n\t"
            "v_pk_fma_f32 v[110:111], v[110:111], %[m1], v[174:175]\n\t"
            "v_pk_fma_f32 v[112:113], v[112:113], %[m1], v[176:177]\n\t"
            "v_pk_fma_f32 v[114:115], v[114:115], %[m1], v[178:179]\n\t"
            "v_pk_fma_f32 v[116:117], v[116:117], %[m1], v[180:181]\n\t"
            "v_pk_fma_f32 v[118:119], v[118:119], %[m1], v[182:183]\n\t"
            "v_pk_fma_f32 v[120:121], v[120:121], %[m1], v[184:185]\n\t"
            "v_pk_fma_f32 v[122:123], v[122:123], %[m1], v[186:187]\n\t"
            "v_pk_fma_f32 v[124:125], v[124:125], %[m1], v[188:189]\n\t"
            "v_pk_fma_f32 v[126:127], v[126:127], %[m1], v[190:191]"
            : "+{v[96:111]}"(wiA), "+{v[112:127]}"(wiB)
            : [m1]"v"(m12), "{v[160:175]}"(twC), "{v[176:191]}"(twD));

        // ---- 10. prefetch x(t+1) — AFTER the WU, where x(t) is dead
        // (R13 lesson: two x generations must never coexist in SGPRs) ----
        {
            const int tn = (t + 1 < TT) ? (t + 1) : (TT - 1);
            const float* xrp = Xr + (size_t)tn * DD;
            const float* xip = Xi + (size_t)tn * DD;
            const float* tgp = Tg + tn;
            SL16(sxr0, xrp, 0x0); SL16(sxr1, xrp, 0x40);
            SL16(sxi0, xip, 0x0); SL16(sxi1, xip, 0x40);
            SL1(stgt, tgp);
        }

        // ---- 11. outputs (fire-and-forget; no vmcnt waits anywhere) ----
        betas[t * NN + n] = bnew;
        if (lane == 63) outs[t] = out;
        beta = bnew;
    }
}

extern "C" void kernel_launch(void* const* d_in, const int* in_sizes, int n_in,
                              void* d_out, int out_size, void* d_ws, size_t ws_size,
                              hipStream_t stream) {
    const float* Xr    = (const float*)d_in[0];   // [T, D]
    const float* Xi    = (const float*)d_in[1];   // [T, D]
    const float* Tg    = (const float*)d_in[2];   // [T]
    const float* W0r   = (const float*)d_in[3];   // [N, D]
    const float* W0i   = (const float*)d_in[4];   // [N, D]
    const float* Phi0  = (const float*)d_in[5];   // [N]
    const float* Beta0 = (const float*)d_in[6];   // [N]

    float* outs   = (float*)d_out;                // [T]
    float* betas  = outs + TT;                    // [T, N]
    float* gammas = betas + (size_t)TT * NN;      // [T, N]

    deerskin<<<1, NN, 0, stream>>>(Xr, Xi, Tg, W0r, W0i, Phi0, Beta0,
                                   outs, betas, gammas);
}

// Round 16
// 7909.953 us; speedup vs baseline: 1.0217x; 1.0217x over previous
//
#include <hip/hip_runtime.h>

#define NN 512
#define DD 32
#define TT 8192

typedef float v4f __attribute__((ext_vector_type(4)));
typedef float v2f __attribute__((ext_vector_type(2)));
typedef float v16f __attribute__((ext_vector_type(16)));
typedef __attribute__((address_space(3))) float lds_f;

constexpr float F_OMEGA = 10.0f;
constexpr float F_DT = 1e-3f;
constexpr float F_TWO_PI = 6.28318530717958647692f;
constexpr float F_INV_TWO_PI = 0.15915494309189533577f;

__device__ __forceinline__ void barrier_lgkm() {
    asm volatile("s_waitcnt lgkmcnt(0)\n\ts_barrier" ::: "memory");
}

#define DSR128(dst, addr, off) \
    asm volatile("ds_read_b128 %0, %1 offset:" #off : "=v"(dst) : "v"(addr))

#define SL16(dst, ptr, off) \
    asm volatile("s_load_dwordx16 %0, %1, " #off : "=s"(dst) : "s"(ptr))
#define SL1(dst, ptr) \
    asm volatile("s_load_dword %0, %1, 0x0" : "=s"(dst) : "s"(ptr))

#define DPP_ADD(x, ctrl, rmask)                                                 \
    {                                                                           \
        int _t = __builtin_amdgcn_update_dpp(0, __float_as_int(x),              \
                                             (ctrl), (rmask), 0xf, true);       \
        (x) += __int_as_float(_t);                                              \
    }

__device__ __forceinline__ float wave_reduce_to_lane63(float x) {
    DPP_ADD(x, 0xB1, 0xf);   // + xor1
    DPP_ADD(x, 0x4E, 0xf);   // + xor2
    DPP_ADD(x, 0x141, 0xf);  // + xor4
    DPP_ADD(x, 0x140, 0xf);  // + xor8
    DPP_ADD(x, 0x142, 0xa);  // row_bcast15
    DPP_ADD(x, 0x143, 0xc);  // row_bcast31
    return x;                // lane 63 = full wave sum
}

// Expand two v16f (SGPR-resident) into 16 v2f pair views (SGPR subregs).
#define MKP(dst, lo, hi)                                                        \
    dst[0]  = __builtin_shufflevector(lo, lo, 0, 1);                            \
    dst[1]  = __builtin_shufflevector(lo, lo, 2, 3);                            \
    dst[2]  = __builtin_shufflevector(lo, lo, 4, 5);                            \
    dst[3]  = __builtin_shufflevector(lo, lo, 6, 7);                            \
    dst[4]  = __builtin_shufflevector(lo, lo, 8, 9);                            \
    dst[5]  = __builtin_shufflevector(lo, lo, 10, 11);                          \
    dst[6]  = __builtin_shufflevector(lo, lo, 12, 13);                          \
    dst[7]  = __builtin_shufflevector(lo, lo, 14, 15);                          \
    dst[8]  = __builtin_shufflevector(hi, hi, 0, 1);                            \
    dst[9]  = __builtin_shufflevector(hi, hi, 2, 3);                            \
    dst[10] = __builtin_shufflevector(hi, hi, 4, 5);                            \
    dst[11] = __builtin_shufflevector(hi, hi, 6, 7);                            \
    dst[12] = __builtin_shufflevector(hi, hi, 8, 9);                            \
    dst[13] = __builtin_shufflevector(hi, hi, 10, 11);                          \
    dst[14] = __builtin_shufflevector(hi, hi, 12, 13);                          \
    dst[15] = __builtin_shufflevector(hi, hi, 14, 15);

// x pair operand lists for the asm blobs (16 "s" inputs each).
#define XIN(x) \
    "s"(x[0]), "s"(x[1]), "s"(x[2]), "s"(x[3]), "s"(x[4]), "s"(x[5]), \
    "s"(x[6]), "s"(x[7]), "s"(x[8]), "s"(x[9]), "s"(x[10]), "s"(x[11]), \
    "s"(x[12]), "s"(x[13]), "s"(x[14]), "s"(x[15])

__global__ __launch_bounds__(512, 2) void deerskin(
    const float* __restrict__ Xr, const float* __restrict__ Xi,
    const float* __restrict__ Tg,
    const float* __restrict__ W0r, const float* __restrict__ W0i,
    const float* __restrict__ Phi0, const float* __restrict__ Beta0,
    float* __restrict__ outs, float* __restrict__ betas, float* __restrict__ gammas)
{
    // Only remaining LDS: 16-float double-buffered partial array.
    __shared__ __align__(16) float sP[16];

    const int n = threadIdx.x;
    const int lane = n & 63;
    const int wid = n >> 6;

    // ---- W state PINNED to physical ArchVGPRs v[64:127] (R6) ----
    v16f wrA, wrB, wiA, wiB;
    {
        const v16f* r = (const v16f*)(W0r + n * DD);
        const v16f* i = (const v16f*)(W0i + n * DD);
        v16f t0 = r[0], t1 = r[1], t2 = i[0], t3 = i[1];
        asm volatile("" : "={v[64:79]}"(wrA) : "0"(t0));
        asm volatile("" : "={v[80:95]}"(wrB) : "0"(t1));
        asm volatile("" : "={v[96:111]}"(wiA) : "0"(t2));
        asm volatile("" : "={v[112:127]}"(wiB) : "0"(t3));
    }

    // ---- tw staging PINNED to v[128:191] ----
    // R12 (best verified, 7899us): tw = g*x(t) is feedback-INDEPENDENT and
    // its 32 pk ops are placed INSIDE the post-barrier stall window (sP
    // ds_read ~120cy + feedback ~100cy). The W update then shrinks to 32
    // feedback-dependent fmas. Busy cycles measured exactly constant vs R6
    // (1872->1873/step); idle fell ~150cy. R14's finer weave was neutral-
    // to-negative (8081): the other wave on the SIMD already covers the
    // feedback dep gaps — window-filling is exhausted at this structure.
    v16f twA, twB, twC, twD;
    {
        v16f z = {0,0,0,0,0,0,0,0,0,0,0,0,0,0,0,0};
        asm volatile("" : "={v[128:143]}"(twA) : "0"(z));
        asm volatile("" : "={v[144:159]}"(twB) : "0"(z));
        asm volatile("" : "={v[160:175]}"(twC) : "0"(z));
        asm volatile("" : "={v[176:191]}"(twD) : "0"(z));
    }

    float phi = Phi0[n];
    float beta = Beta0[n];
    float lt = 0.0f;
    float err = 0.0f;

    // Loop-carried SGPR-resident x(t).
    v16f sxr0, sxr1, sxi0, sxi1;
    float stgt;

    // ---- prologue: issue x(0) scalar loads (drained by the t=0 tie-wait).
    SL16(sxr0, Xr, 0x0); SL16(sxr1, Xr, 0x40);
    SL16(sxi0, Xi, 0x0); SL16(sxi1, Xi, 0x40);
    SL1(stgt, Tg);

    for (int t = 0; t < TT; ++t) {
        // ---- 1. x-independent precompute (beta-dependent arm) ----
        const float gamma = __expf(-0.5f * beta);
        const float dtl = gamma * F_DT;
        lt += dtl;
        const float theta = fmaf(F_OMEGA, lt, phi);
        float rev = theta * F_INV_TWO_PI;
        rev -= floorf(rev);
        const float s = __builtin_amdgcn_sinf(rev);
        const float c = __builtin_amdgcn_cosf(rev);
        const float a_sA = 1.0f - __expf(-2.0f * F_DT * (gamma + 1e-6f));
        const float a_sB = 1.0f - __expf(-F_DT / 0.03f);

        // ---- 2. tie-wait for x(t) ----
        asm volatile("s_waitcnt lgkmcnt(0)"
            : "+s"(sxr0), "+s"(sxr1), "+s"(sxi0), "+s"(sxi1), "+s"(stgt)
            :: "memory");
        const float tgt = stgt;

        v2f xr_[16], xi_[16];
        MKP(xr_, sxr0, sxr1);
        MKP(xi_, sxi0, sxi1);

        // ---- 3. Z = W @ x: two blobs, pinned-W pairs referenced directly.
        // Chain order per accumulator identical to R5/R6 -> bit-identical FP.
        v2f arr0, arr1, aii0, aii1, ari0, ari1, air0, air1;
        asm volatile(
            "v_pk_mul_f32 %0, v[64:65], %8\n\t"
            "v_pk_mul_f32 %1, v[66:67], %9\n\t"
            "v_pk_mul_f32 %2, v[96:97], %8\n\t"
            "v_pk_mul_f32 %3, v[98:99], %9\n\t"
            "v_pk_fma_f32 %0, v[68:69], %10, %0\n\t"
            "v_pk_fma_f32 %1, v[70:71], %11, %1\n\t"
            "v_pk_fma_f32 %2, v[100:101], %10, %2\n\t"
            "v_pk_fma_f32 %3, v[102:103], %11, %3\n\t"
            "v_pk_fma_f32 %0, v[72:73], %12, %0\n\t"
            "v_pk_fma_f32 %1, v[74:75], %13, %1\n\t"
            "v_pk_fma_f32 %2, v[104:105], %12, %2\n\t"
            "v_pk_fma_f32 %3, v[106:107], %13, %3\n\t"
            "v_pk_fma_f32 %0, v[76:77], %14, %0\n\t"
            "v_pk_fma_f32 %1, v[78:79], %15, %1\n\t"
            "v_pk_fma_f32 %2, v[108:109], %14, %2\n\t"
            "v_pk_fma_f32 %3, v[110:111], %15, %3\n\t"
            "v_pk_fma_f32 %0, v[80:81], %16, %0\n\t"
            "v_pk_fma_f32 %1, v[82:83], %17, %1\n\t"
            "v_pk_fma_f32 %2, v[112:113], %16, %2\n\t"
            "v_pk_fma_f32 %3, v[114:115], %17, %3\n\t"
            "v_pk_fma_f32 %0, v[84:85], %18, %0\n\t"
            "v_pk_fma_f32 %1, v[86:87], %19, %1\n\t"
            "v_pk_fma_f32 %2, v[116:117], %18, %2\n\t"
            "v_pk_fma_f32 %3, v[118:119], %19, %3\n\t"
            "v_pk_fma_f32 %0, v[88:89], %20, %0\n\t"
            "v_pk_fma_f32 %1, v[90:91], %21, %1\n\t"
            "v_pk_fma_f32 %2, v[120:121], %20, %2\n\t"
            "v_pk_fma_f32 %3, v[122:123], %21, %3\n\t"
            "v_pk_fma_f32 %0, v[92:93], %22, %0\n\t"
            "v_pk_fma_f32 %1, v[94:95], %23, %1\n\t"
            "v_pk_fma_f32 %2, v[124:125], %22, %2\n\t"
            "v_pk_fma_f32 %3, v[126:127], %23, %3"
            : "=&v"(arr0), "=&v"(arr1), "=&v"(air0), "=&v"(air1)
            : "{v[64:79]}"(wrA), "{v[80:95]}"(wrB),
              "{v[96:111]}"(wiA), "{v[112:127]}"(wiB), XIN(xr_));
        asm volatile(
            "v_pk_mul_f32 %0, v[96:97], %8\n\t"
            "v_pk_mul_f32 %1, v[98:99], %9\n\t"
            "v_pk_mul_f32 %2, v[64:65], %8\n\t"
            "v_pk_mul_f32 %3, v[66:67], %9\n\t"
            "v_pk_fma_f32 %0, v[100:101], %10, %0\n\t"
            "v_pk_fma_f32 %1, v[102:103], %11, %1\n\t"
            "v_pk_fma_f32 %2, v[68:69], %10, %2\n\t"
            "v_pk_fma_f32 %3, v[70:71], %11, %3\n\t"
            "v_pk_fma_f32 %0, v[104:105], %12, %0\n\t"
            "v_pk_fma_f32 %1, v[106:107], %13, %1\n\t"
            "v_pk_fma_f32 %2, v[72:73], %12, %2\n\t"
            "v_pk_fma_f32 %3, v[74:75], %13, %3\n\t"
            "v_pk_fma_f32 %0, v[108:109], %14, %0\n\t"
            "v_pk_fma_f32 %1, v[110:111], %15, %1\n\t"
            "v_pk_fma_f32 %2, v[76:77], %14, %2\n\t"
            "v_pk_fma_f32 %3, v[78:79], %15, %3\n\t"
            "v_pk_fma_f32 %0, v[112:113], %16, %0\n\t"
            "v_pk_fma_f32 %1, v[114:115], %17, %1\n\t"
            "v_pk_fma_f32 %2, v[80:81], %16, %2\n\t"
            "v_pk_fma_f32 %3, v[82:83], %17, %3\n\t"
            "v_pk_fma_f32 %0, v[116:117], %18, %0\n\t"
            "v_pk_fma_f32 %1, v[118:119], %19, %1\n\t"
            "v_pk_fma_f32 %2, v[84:85], %18, %2\n\t"
            "v_pk_fma_f32 %3, v[86:87], %19, %3\n\t"
            "v_pk_fma_f32 %0, v[120:121], %20, %0\n\t"
            "v_pk_fma_f32 %1, v[122:123], %21, %1\n\t"
            "v_pk_fma_f32 %2, v[88:89], %20, %2\n\t"
            "v_pk_fma_f32 %3, v[90:91], %21, %3\n\t"
            "v_pk_fma_f32 %0, v[124:125], %22, %0\n\t"
            "v_pk_fma_f32 %1, v[126:127], %23, %1\n\t"
            "v_pk_fma_f32 %2, v[92:93], %22, %2\n\t"
            "v_pk_fma_f32 %3, v[94:95], %23, %3"
            : "=&v"(aii0), "=&v"(aii1), "=&v"(ari0), "=&v"(ari1)
            : "{v[64:79]}"(wrA), "{v[80:95]}"(wrB),
              "{v[96:111]}"(wiA), "{v[112:127]}"(wiB), XIN(xi_));

        const float hArr = (arr0.x + arr0.y) + (arr1.x + arr1.y);
        const float hAii = (aii0.x + aii0.y) + (aii1.x + aii1.y);
        const float hAri = (ari0.x + ari0.y) + (ari1.x + ari1.y);
        const float hAir = (air0.x + air0.y) + (air1.x + air1.y);
        const float zr = hArr - hAii;
        const float zi = hAri + hAir;

        // Y = |Z| * relu(cos(theta - angle(Z))) == relu(zr*cos + zi*sin)
        const float Y = fmaxf(fmaf(zr, c, zi * s), 0.0f);

        // ---- 4. reduce 512 -> 1: DPP wave sum, 8 partials via LDS ----
        float v = wave_reduce_to_lane63(Y * c);
        if (lane == 63) sP[((t & 1) << 3) + wid] = v;

        // ---- 5. pre-barrier tail ----
        const float inv_t = 1.0f / (fabsf(tgt) + 0.01f);
        const float yy = Y * Y;
        const float g = 0.05f * Y * dtl;
        const v2f g2 = {g, g};
        phi += (2.0f / (float)NN) * (-tgt * s) * dtl;
        phi = phi - F_TWO_PI * floorf(phi * F_INV_TWO_PI);
        gammas[t * NN + n] = gamma;   // gamma from OLD beta, per reference

        // ---- 6. barrier (drains only lane63's sP ds_write) ----
        barrier_lgkm();

        // ---- 7. sP reads ISSUED, then tw = g*x(t) fills the read latency
        // and the feedback window: 32 pk of feedback-independent issue
        // inside the formerly-dead stall window.
        const unsigned lsp =
            (unsigned)(unsigned long long)(lds_f*)&sP[(t & 1) << 3];
        v4f p0, p1;
        DSR128(p0, lsp, 0); DSR128(p1, lsp, 16);
        asm volatile(
            "v_pk_mul_f32 v[128:129], %[g2], %[x0]\n\t"
            "v_pk_mul_f32 v[130:131], %[g2], %[x1]\n\t"
            "v_pk_mul_f32 v[132:133], %[g2], %[x2]\n\t"
            "v_pk_mul_f32 v[134:135], %[g2], %[x3]\n\t"
            "v_pk_mul_f32 v[136:137], %[g2], %[x4]\n\t"
            "v_pk_mul_f32 v[138:139], %[g2], %[x5]\n\t"
            "v_pk_mul_f32 v[140:141], %[g2], %[x6]\n\t"
            "v_pk_mul_f32 v[142:143], %[g2], %[x7]\n\t"
            "v_pk_mul_f32 v[144:145], %[g2], %[x8]\n\t"
            "v_pk_mul_f32 v[146:147], %[g2], %[x9]\n\t"
            "v_pk_mul_f32 v[148:149], %[g2], %[x10]\n\t"
            "v_pk_mul_f32 v[150:151], %[g2], %[x11]\n\t"
            "v_pk_mul_f32 v[152:153], %[g2], %[x12]\n\t"
            "v_pk_mul_f32 v[154:155], %[g2], %[x13]\n\t"
            "v_pk_mul_f32 v[156:157], %[g2], %[x14]\n\t"
            "v_pk_mul_f32 v[158:159], %[g2], %[x15]"
            : "+{v[128:143]}"(twA), "+{v[144:159]}"(twB)
            : [g2]"v"(g2),
              [x0]"s"(xr_[0]), [x1]"s"(xr_[1]), [x2]"s"(xr_[2]), [x3]"s"(xr_[3]),
              [x4]"s"(xr_[4]), [x5]"s"(xr_[5]), [x6]"s"(xr_[6]), [x7]"s"(xr_[7]),
              [x8]"s"(xr_[8]), [x9]"s"(xr_[9]), [x10]"s"(xr_[10]), [x11]"s"(xr_[11]),
              [x12]"s"(xr_[12]), [x13]"s"(xr_[13]), [x14]"s"(xr_[14]), [x15]"s"(xr_[15]));
        asm volatile(
            "v_pk_mul_f32 v[160:161], %[g2], %[x0]\n\t"
            "v_pk_mul_f32 v[162:163], %[g2], %[x1]\n\t"
            "v_pk_mul_f32 v[164:165], %[g2], %[x2]\n\t"
            "v_pk_mul_f32 v[166:167], %[g2], %[x3]\n\t"
            "v_pk_mul_f32 v[168:169], %[g2], %[x4]\n\t"
            "v_pk_mul_f32 v[170:171], %[g2], %[x5]\n\t"
            "v_pk_mul_f32 v[172:173], %[g2], %[x6]\n\t"
            "v_pk_mul_f32 v[174:175], %[g2], %[x7]\n\t"
            "v_pk_mul_f32 v[176:177], %[g2], %[x8]\n\t"
            "v_pk_mul_f32 v[178:179], %[g2], %[x9]\n\t"
            "v_pk_mul_f32 v[180:181], %[g2], %[x10]\n\t"
            "v_pk_mul_f32 v[182:183], %[g2], %[x11]\n\t"
            "v_pk_mul_f32 v[184:185], %[g2], %[x12]\n\t"
            "v_pk_mul_f32 v[186:187], %[g2], %[x13]\n\t"
            "v_pk_mul_f32 v[188:189], %[g2], %[x14]\n\t"
            "v_pk_mul_f32 v[190:191], %[g2], %[x15]"
            : "+{v[160:175]}"(twC), "+{v[176:191]}"(twD)
            : [g2]"v"(g2),
              [x0]"s"(xi_[0]), [x1]"s"(xi_[1]), [x2]"s"(xi_[2]), [x3]"s"(xi_[3]),
              [x4]"s"(xi_[4]), [x5]"s"(xi_[5]), [x6]"s"(xi_[6]), [x7]"s"(xi_[7]),
              [x8]"s"(xi_[8]), [x9]"s"(xi_[9]), [x10]"s"(xi_[10]), [x11]"s"(xi_[11]),
              [x12]"s"(xi_[12]), [x13]"s"(xi_[13]), [x14]"s"(xi_[14]), [x15]"s"(xi_[15]));

        asm volatile("s_waitcnt lgkmcnt(0)" : "+v"(p0), "+v"(p1) :: "memory");

        // ---- 8. out + short scalar feedback chain ----
        const float out = ((p0.x + p0.y) + (p0.z + p0.w)) +
                          ((p1.x + p1.y) + (p1.z + p1.w));
        const float raw = fabsf(tgt - out);
        err = 0.99f * err + 0.01f * raw;
        const float rel = err * inv_t;
        const float btg = 3.5f * __expf(-5.0f * rel);
        const float a_s = (btg > beta) ? a_sA : a_sB;
        float bnew = beta + a_s * (btg - beta);
        bnew = fminf(fmaxf(bnew, 0.005f), 5.0f);

        // ---- 9. W = W*m1 + tw: only 32 feedback-dependent fmas remain ----
        const float k = (bnew * yy) * dtl;
        const float m1 = 1.0f - k;
        const v2f m12 = {m1, m1};
        asm volatile(
            "v_pk_fma_f32 v[64:65], v[64:65], %[m1], v[128:129]\n\t"
            "v_pk_fma_f32 v[66:67], v[66:67], %[m1], v[130:131]\n\t"
            "v_pk_fma_f32 v[68:69], v[68:69], %[m1], v[132:133]\n\t"
            "v_pk_fma_f32 v[70:71], v[70:71], %[m1], v[134:135]\n\t"
            "v_pk_fma_f32 v[72:73], v[72:73], %[m1], v[136:137]\n\t"
            "v_pk_fma_f32 v[74:75], v[74:75], %[m1], v[138:139]\n\t"
            "v_pk_fma_f32 v[76:77], v[76:77], %[m1], v[140:141]\n\t"
            "v_pk_fma_f32 v[78:79], v[78:79], %[m1], v[142:143]\n\t"
            "v_pk_fma_f32 v[80:81], v[80:81], %[m1], v[144:145]\n\t"
            "v_pk_fma_f32 v[82:83], v[82:83], %[m1], v[146:147]\n\t"
            "v_pk_fma_f32 v[84:85], v[84:85], %[m1], v[148:149]\n\t"
            "v_pk_fma_f32 v[86:87], v[86:87], %[m1], v[150:151]\n\t"
            "v_pk_fma_f32 v[88:89], v[88:89], %[m1], v[152:153]\n\t"
            "v_pk_fma_f32 v[90:91], v[90:91], %[m1], v[154:155]\n\t"
            "v_pk_fma_f32 v[92:93], v[92:93], %[m1], v[156:157]\n\t"
            "v_pk_fma_f32 v[94:95], v[94:95], %[m1], v[158:159]"
            : "+{v[64:79]}"(wrA), "+{v[80:95]}"(wrB)
            : [m1]"v"(m12), "{v[128:143]}"(twA), "{v[144:159]}"(twB));
        asm volatile(
            "v_pk_fma_f32 v[96:97], v[96:97], %[m1], v[160:161]\n\t"
            "v_pk_fma_f32 v[98:99], v[98:99], %[m1], v[162:163]\n\t"
            "v_pk_fma_f32 v[100:101], v[100:101], %[m1], v[164:165]\n\t"
            "v_pk_fma_f32 v[102:103], v[102:103], %[m1], v[166:167]\n\t"
            "v_pk_fma_f32 v[104:105], v[104:105], %[m1], v[168:169]\n\t"
            "v_pk_fma_f32 v[106:107], v[106:107], %[m1], v[170:171]\n\t"
            "v_pk_fma_f32 v[108:109], v[108:109], %[m1], v[172:173]\n\t"
            "v_pk_fma_f32 v[110:111], v[110:111], %[m1], v[174:175]\n\t"
            "v_pk_fma_f32 v[112:113], v[112:113], %[m1], v[176:177]\n\t"
            "v_pk_fma_f32 v[114:115], v[114:115], %[m1], v[178:179]\n\t"
            "v_pk_fma_f32 v[116:117], v[116:117], %[m1], v[180:181]\n\t"
            "v_pk_fma_f32 v[118:119], v[118:119], %[m1], v[182:183]\n\t"
            "v_pk_fma_f32 v[120:121], v[120:121], %[m1], v[184:185]\n\t"
            "v_pk_fma_f32 v[122:123], v[122:123], %[m1], v[186:187]\n\t"
            "v_pk_fma_f32 v[124:125], v[124:125], %[m1], v[188:189]\n\t"
            "v_pk_fma_f32 v[126:127], v[126:127], %[m1], v[190:191]"
            : "+{v[96:111]}"(wiA), "+{v[112:127]}"(wiB)
            : [m1]"v"(m12), "{v[160:175]}"(twC), "{v[176:191]}"(twD));

        // ---- 10. prefetch x(t+1) (x(t) dead after tw) ----
        {
            const int tn = (t + 1 < TT) ? (t + 1) : (TT - 1);
            const float* xrp = Xr + (size_t)tn * DD;
            const float* xip = Xi + (size_t)tn * DD;
            const float* tgp = Tg + tn;
            SL16(sxr0, xrp, 0x0); SL16(sxr1, xrp, 0x40);
            SL16(sxi0, xip, 0x0); SL16(sxi1, xip, 0x40);
            SL1(stgt, tgp);
        }

        // ---- 11. outputs (fire-and-forget; no vmcnt waits anywhere) ----
        betas[t * NN + n] = bnew;
        if (lane == 63) outs[t] = out;
        beta = bnew;
    }
}

extern "C" void kernel_launch(void* const* d_in, const int* in_sizes, int n_in,
                              void* d_out, int out_size, void* d_ws, size_t ws_size,
                              hipStream_t stream) {
    const float* Xr    = (const float*)d_in[0];   // [T, D]
    const float* Xi    = (const float*)d_in[1];   // [T, D]
    const float* Tg    = (const float*)d_in[2];   // [T]
    const float* W0r   = (const float*)d_in[3];   // [N, D]
    const float* W0i   = (const float*)d_in[4];   // [N, D]
    const float* Phi0  = (const float*)d_in[5];   // [N]
    const float* Beta0 = (const float*)d_in[6];   // [N]

    float* outs   = (float*)d_out;                // [T]
    float* betas  = outs + TT;                    // [T, N]
    float* gammas = betas + (size_t)TT * NN;      // [T, N]

    deerskin<<<1, NN, 0, stream>>>(Xr, Xi, Tg, W0r, W0i, Phi0, Beta0,
                                   outs, betas, gammas);
}